// Round 1
// 773.096 us; speedup vs baseline: 1.0620x; 1.0620x over previous
//
#include <hip/hip_runtime.h>
#include <hip/hip_bf16.h>

// Problem constants (B=2,S=2048,H=1024,I=2816,E=7,TOPK=2)
#define NTOK 4096         // B*S
#define HH 1024
#define II 2816
#define EE 7
#define SHARED_BASE 8192  // NTOK*TOPK routed slots, then NTOK shared slots
#define NSLOT 12288       // 8192 + 4096

typedef __bf16 bf16x8 __attribute__((ext_vector_type(8)));
typedef __bf16 bf16x4 __attribute__((ext_vector_type(4)));
typedef float  f32x4v __attribute__((ext_vector_type(4)));

// global->LDS direct DMA, 16B per lane. LDS dest must be linear in lane order
// (wave-uniform base + lane*16); global src may be fully per-lane.
typedef const __attribute__((address_space(1))) void* gas_ptr;
typedef __attribute__((address_space(3))) void* las_ptr;
__device__ __forceinline__ void load16_lds(const void* g, void* l) {
    __builtin_amdgcn_global_load_lds((gas_ptr)g, (las_ptr)l, 16, 0, 0);
}

// ---------------------------------------------------------------- cvt x->bf16
__global__ void cvt_x(const float* __restrict__ x, __bf16* __restrict__ xb) {
    int i = blockIdx.x * blockDim.x + threadIdx.x;   // 262144 threads
    const f32x4v* xv = (const f32x4v*)x;
    bf16x4* ov = (bf16x4*)xb;
    int base = i * 4;                                 // 4 float4 per thread
#pragma unroll
    for (int j = 0; j < 4; j++) {
        f32x4v f = xv[base + j];
        bf16x4 b;
        b[0] = (__bf16)f[0]; b[1] = (__bf16)f[1];
        b[2] = (__bf16)f[2]; b[3] = (__bf16)f[3];
        ov[base + j] = b;
    }
}

// ---------------------------------------------------------------- cvt weights
// One launch, grid.y in [0,6): Wg,Wu,Wd (big) then Wgs,Wus,Wds (small).
__global__ void cvt_w6(const float* __restrict__ s0, const float* __restrict__ s1,
                       const float* __restrict__ s2, const float* __restrict__ s3,
                       const float* __restrict__ s4, const float* __restrict__ s5,
                       __bf16* __restrict__ d0, __bf16* __restrict__ d1,
                       __bf16* __restrict__ d2, __bf16* __restrict__ d3,
                       __bf16* __restrict__ d4, __bf16* __restrict__ d5) {
    const int y = blockIdx.y;
    const float* s; __bf16* d; int n4;
    if (y == 0)      { s = s0; d = d0; n4 = (EE * II * HH) / 4; }
    else if (y == 1) { s = s1; d = d1; n4 = (EE * II * HH) / 4; }
    else if (y == 2) { s = s2; d = d2; n4 = (EE * II * HH) / 4; }
    else if (y == 3) { s = s3; d = d3; n4 = (II * HH) / 4; }
    else if (y == 4) { s = s4; d = d4; n4 = (II * HH) / 4; }
    else             { s = s5; d = d5; n4 = (II * HH) / 4; }
    const f32x4v* sv = (const f32x4v*)s;
    bf16x4* dv = (bf16x4*)d;
    for (int i = blockIdx.x * blockDim.x + threadIdx.x; i < n4;
         i += gridDim.x * blockDim.x) {
        f32x4v f = sv[i];
        bf16x4 b;
        b[0] = (__bf16)f[0]; b[1] = (__bf16)f[1];
        b[2] = (__bf16)f[2]; b[3] = (__bf16)f[3];
        dv[i] = b;
    }
}

// ---------------------------------------------------------------- router
// One wave per token. fp64 accumulation so top-2 selection matches the
// reference even near ties.
__global__ void router_k(const float* __restrict__ x, const float* __restrict__ Wr,
                         float* __restrict__ logits, int* __restrict__ counts,
                         int* __restrict__ sel, float* __restrict__ wtop,
                         int* __restrict__ tlist, float* __restrict__ wlist) {
    int wave = threadIdx.x >> 6;
    int lane = threadIdx.x & 63;
    int t = blockIdx.x * 4 + wave;
    const float* xr = x + (size_t)t * HH;
    double acc[EE];
#pragma unroll
    for (int e = 0; e < EE; e++) acc[e] = 0.0;
    for (int j = 0; j < 16; j++) {
        int h = lane + j * 64;
        double xv = (double)xr[h];
#pragma unroll
        for (int e = 0; e < EE; e++) acc[e] += xv * (double)Wr[e * HH + h];
    }
#pragma unroll
    for (int e = 0; e < EE; e++) {
        for (int off = 32; off > 0; off >>= 1) acc[e] += __shfl_down(acc[e], off, 64);
    }
    if (lane == 0) {
        int e0 = 0;
        for (int e = 1; e < EE; e++) if (acc[e] > acc[e0]) e0 = e;
        int e1 = -1;
        for (int e = 0; e < EE; e++) {
            if (e == e0) continue;
            if (e1 < 0 || acc[e] > acc[e1]) e1 = e;
        }
        double w1 = exp(acc[e1] - acc[e0]);
        double s = 1.0 + w1;
        for (int e = 0; e < EE; e++) logits[(size_t)t * EE + e] = (float)acc[e];
        sel[2 * t] = e0; sel[2 * t + 1] = e1;
        wtop[2 * t] = (float)(1.0 / s); wtop[2 * t + 1] = (float)(w1 / s);
        atomicAdd(&counts[e0], 1);
        atomicAdd(&counts[e1], 1);
        tlist[SHARED_BASE + t] = t;
        wlist[SHARED_BASE + t] = 1.0f;
    }
}

// ---------------------------------------------------------------- finalize
__global__ void finalize_k(const int* __restrict__ counts, int* __restrict__ cursor,
                           int* __restrict__ nlist, int* __restrict__ offs) {
    if (threadIdx.x == 0 && blockIdx.x == 0) {
        int o = 0;
        for (int e = 0; e < EE; e++) {
            offs[e] = o; cursor[e] = o; nlist[e] = counts[e];
            o += counts[e];
        }
        offs[EE] = SHARED_BASE;
        nlist[EE] = NTOK;
        cursor[EE] = SHARED_BASE;
    }
}

// ---------------------------------------------------------------- scatter
__global__ void scatter_k(const int* __restrict__ sel, const float* __restrict__ wtop,
                          int* __restrict__ cursor, int* __restrict__ tlist,
                          float* __restrict__ wlist) {
    int t = blockIdx.x * blockDim.x + threadIdx.x;
    if (t >= NTOK) return;
#pragma unroll
    for (int j = 0; j < 2; j++) {
        int e = sel[2 * t + j];
        int slot = atomicAdd(&cursor[e], 1);
        tlist[slot] = t;
        wlist[slot] = wtop[2 * t + j];
    }
}

// ================================================================ FAST PATH
// gate+up GEMM, bf16 weights, global_load_lds staging (m97 structure).
// Block tile 128(M) x 64(N), BK=32, 4 waves (2x2), wave tile 64x32 per output.
// All staging is 4x global_load_lds_dwordx4/thread/K-step; no ds_write, no
// fp32->bf16 repack in the loop. Source-side XOR chunk swizzle (c ^= (row>>1)&3,
// 16B granularity) + identical XOR on ds_read addr -> 2-way residual bank
// aliasing (free per m136). XCD swizzle keeps one expert N-panel per XCD L2.
__global__ __launch_bounds__(256, 3) void gateup_bf(
        const __bf16* __restrict__ Wg, const __bf16* __restrict__ Wu,
        const __bf16* __restrict__ Wgs, const __bf16* __restrict__ Wus,
        const __bf16* __restrict__ xb, __bf16* __restrict__ hbuf,
        const int* __restrict__ nlist, const int* __restrict__ offs,
        const int* __restrict__ tlist) {
    const int e = blockIdx.z;
    const int ne = nlist[e];
    const int bx = blockIdx.x;                 // 1536 per expert (48 nt' x 32 mt)
    const int nt = (bx & 7) + 8 * (bx >> 8);   // XCD = nt % 8
    const int mt = (bx >> 3) & 31;
    if (nt >= II / 64) return;                 // 44 real panels
    if (mt * 128 >= ne) return;
    const int base = offs[e];
    const __bf16* wg = (e < EE) ? Wg + (size_t)e * II * HH : Wgs;
    const __bf16* wu = (e < EE) ? Wu + (size_t)e * II * HH : Wus;

    __shared__ __bf16 As[128 * 32];   // 8 KB
    __shared__ __bf16 Bg[64 * 32];    // 4 KB
    __shared__ __bf16 Bu[64 * 32];    // 4 KB

    const int tid = threadIdx.x;
    const int r0 = tid >> 2;                   // row 0..63 (A also row+64)
    const int c  = tid & 3;                    // 16B chunk 0..3
    const int cs = (c ^ ((r0 >> 1) & 3)) * 8;  // swizzled source chunk (elems)
    const int cl0 = min(mt * 128 + r0, ne - 1);
    const int cl1 = min(mt * 128 + r0 + 64, ne - 1);
    const __bf16* aptr0 = xb + (size_t)tlist[base + cl0] * HH + cs;
    const __bf16* aptr1 = xb + (size_t)tlist[base + cl1] * HH + cs;
    const __bf16* bgp = wg + (size_t)(nt * 64 + r0) * HH + cs;
    const __bf16* bup = wu + (size_t)(nt * 64 + r0) * HH + cs;
    __bf16* ldsA0 = &As[tid * 8];              // linear lane order, 16B/lane
    __bf16* ldsA1 = &As[64 * 32 + tid * 8];
    __bf16* ldsBg = &Bg[tid * 8];
    __bf16* ldsBu = &Bu[tid * 8];

    const int wid = tid >> 6, lane = tid & 63;
    const int wm = wid >> 1, wn = wid & 1;
    const int l16 = lane & 15, quad = lane >> 4;
    const int qsw = (quad ^ ((l16 >> 1) & 3)) * 8;   // read-side swizzle (elems)

    f32x4v accg[4][2], accu[4][2];
#pragma unroll
    for (int i = 0; i < 4; i++)
#pragma unroll
        for (int j = 0; j < 2; j++) { accg[i][j] = (f32x4v)0.0f; accu[i][j] = (f32x4v)0.0f; }

    for (int k0 = 0; k0 < HH; k0 += 32) {
        __syncthreads();                       // prev MFMA reads done
        load16_lds(aptr0 + k0, ldsA0);
        load16_lds(aptr1 + k0, ldsA1);
        load16_lds(bgp + k0, ldsBg);
        load16_lds(bup + k0, ldsBu);
        __syncthreads();                       // vmcnt drained before barrier
        bf16x8 a[4];
#pragma unroll
        for (int i = 0; i < 4; i++)
            a[i] = *(const bf16x8*)&As[(wm * 64 + i * 16 + l16) * 32 + qsw];
#pragma unroll
        for (int j = 0; j < 2; j++) {
            bf16x8 bg = *(const bf16x8*)&Bg[(wn * 32 + j * 16 + l16) * 32 + qsw];
            bf16x8 bu = *(const bf16x8*)&Bu[(wn * 32 + j * 16 + l16) * 32 + qsw];
#pragma unroll
            for (int i = 0; i < 4; i++) {
                accg[i][j] = __builtin_amdgcn_mfma_f32_16x16x32_bf16(a[i], bg, accg[i][j], 0, 0, 0);
                accu[i][j] = __builtin_amdgcn_mfma_f32_16x16x32_bf16(a[i], bu, accu[i][j], 0, 0, 0);
            }
        }
    }
    // epilogue: h = silu(g)*u -> bf16
#pragma unroll
    for (int i = 0; i < 4; i++) {
        const int mrow = mt * 128 + wm * 64 + i * 16 + quad * 4;
#pragma unroll
        for (int r = 0; r < 4; r++) {
            const int slot = mrow + r;
            if (slot < ne) {
                __bf16* hrow = hbuf + (size_t)(base + slot) * II + nt * 64 + wn * 32 + l16;
#pragma unroll
                for (int j = 0; j < 2; j++) {
                    float g = accg[i][j][r], u = accu[i][j][r];
                    float sgl = g / (1.0f + __expf(-g));
                    hrow[j * 16] = (__bf16)(sgl * u);
                }
            }
        }
    }
}

// down proj, bf16 weights, global_load_lds staging. Block 128(M)x128(N),
// BK=32, wave tile 64x64. Same swizzle scheme.
__global__ __launch_bounds__(256, 3) void down_bf(
        const __bf16* __restrict__ Wd, const __bf16* __restrict__ Wds,
        const __bf16* __restrict__ hbuf, float* __restrict__ out,
        const int* __restrict__ nlist, const int* __restrict__ offs,
        const int* __restrict__ tlist, const float* __restrict__ wlist) {
    const int e = blockIdx.z;
    const int ne = nlist[e];
    const int bx = blockIdx.x;                 // [0,256): 8 nt x 32 mt
    const int nt = bx & 7;                     // XCD = nt
    const int mt = bx >> 3;
    if (mt * 128 >= ne) return;
    const int base = offs[e];
    const __bf16* wd = (e < EE) ? Wd + (size_t)e * HH * II : Wds;

    __shared__ __bf16 As[128 * 32];   // 8 KB
    __shared__ __bf16 Bs[128 * 32];   // 8 KB

    const int tid = threadIdx.x;
    const int r0 = tid >> 2;
    const int c  = tid & 3;
    const int cs = (c ^ ((r0 >> 1) & 3)) * 8;
    const int cl0 = min(mt * 128 + r0, ne - 1);
    const int cl1 = min(mt * 128 + r0 + 64, ne - 1);
    const __bf16* aptr0 = hbuf + (size_t)(base + cl0) * II + cs;
    const __bf16* aptr1 = hbuf + (size_t)(base + cl1) * II + cs;
    const __bf16* bptr0 = wd + (size_t)(nt * 128 + r0) * II + cs;
    const __bf16* bptr1 = wd + (size_t)(nt * 128 + r0 + 64) * II + cs;
    __bf16* ldsA0 = &As[tid * 8];
    __bf16* ldsA1 = &As[64 * 32 + tid * 8];
    __bf16* ldsB0 = &Bs[tid * 8];
    __bf16* ldsB1 = &Bs[64 * 32 + tid * 8];

    const int wid = tid >> 6, lane = tid & 63;
    const int wm = wid >> 1, wn = wid & 1;
    const int l16 = lane & 15, quad = lane >> 4;
    const int qsw = (quad ^ ((l16 >> 1) & 3)) * 8;

    f32x4v acc[4][4];
#pragma unroll
    for (int i = 0; i < 4; i++)
#pragma unroll
        for (int j = 0; j < 4; j++) acc[i][j] = (f32x4v)0.0f;

    for (int k0 = 0; k0 < II; k0 += 32) {
        __syncthreads();
        load16_lds(aptr0 + k0, ldsA0);
        load16_lds(aptr1 + k0, ldsA1);
        load16_lds(bptr0 + k0, ldsB0);
        load16_lds(bptr1 + k0, ldsB1);
        __syncthreads();
        bf16x8 a[4];
#pragma unroll
        for (int i = 0; i < 4; i++)
            a[i] = *(const bf16x8*)&As[(wm * 64 + i * 16 + l16) * 32 + qsw];
#pragma unroll
        for (int j = 0; j < 4; j++) {
            bf16x8 b = *(const bf16x8*)&Bs[(wn * 64 + j * 16 + l16) * 32 + qsw];
#pragma unroll
            for (int i = 0; i < 4; i++)
                acc[i][j] = __builtin_amdgcn_mfma_f32_16x16x32_bf16(a[i], b, acc[i][j], 0, 0, 0);
        }
    }
    // epilogue: out[token] += w_slot * acc
#pragma unroll
    for (int i = 0; i < 4; i++) {
        const int mrow = mt * 128 + wm * 64 + i * 16 + quad * 4;
#pragma unroll
        for (int r = 0; r < 4; r++) {
            const int slot = mrow + r;
            if (slot < ne) {
                const int idx = base + slot;
                const int tok = tlist[idx];
                const float w = wlist[idx];
                float* orow = out + (size_t)tok * HH + nt * 128 + wn * 64 + l16;
#pragma unroll
                for (int j = 0; j < 4; j++)
                    atomicAdd(&orow[j * 16], w * acc[i][j][r]);
            }
        }
    }
}

// ================================================================ FALLBACK
// Previous verified kernels (fp32 weights, reg-staged) — used only if the
// workspace is too small for the bf16 weight buffers.
__global__ __launch_bounds__(256, 3) void gateup_f32(
        const float* __restrict__ Wg, const float* __restrict__ Wu,
        const float* __restrict__ Wgs, const float* __restrict__ Wus,
        const __bf16* __restrict__ xb, __bf16* __restrict__ hbuf,
        const int* __restrict__ nlist, const int* __restrict__ offs,
        const int* __restrict__ tlist) {
    const int e = blockIdx.z;
    const int ne = nlist[e];
    const int bx = blockIdx.x;
    const int nt = (bx & 7) + 8 * (bx >> 8);
    const int mt = (bx >> 3) & 31;
    if (nt >= II / 64) return;
    if (mt * 128 >= ne) return;
    const int base = offs[e];
    const float* wg = (e < EE) ? Wg + (size_t)e * II * HH : Wgs;
    const float* wu = (e < EE) ? Wu + (size_t)e * II * HH : Wus;

    __shared__ __bf16 As[128 * 32];
    __shared__ __bf16 Bg[64 * 32];
    __shared__ __bf16 Bu[64 * 32];

    const int tid = threadIdx.x;
    const int arow0 = tid >> 2, c8 = (tid & 3) * 8;
    const int arow1 = arow0 + 64;
    const int cl0 = min(mt * 128 + arow0, ne - 1);
    const int cl1 = min(mt * 128 + arow1, ne - 1);
    const __bf16* aptr0 = xb + (size_t)tlist[base + cl0] * HH + c8;
    const __bf16* aptr1 = xb + (size_t)tlist[base + cl1] * HH + c8;
    const int brow = tid >> 2;
    const size_t boff = (size_t)(nt * 64 + brow) * HH + c8;

    const int wid = tid >> 6, lane = tid & 63;
    const int wm = wid >> 1, wn = wid & 1;
    const int l16 = lane & 15, quad = lane >> 4;

    f32x4v accg[4][2], accu[4][2];
#pragma unroll
    for (int i = 0; i < 4; i++)
#pragma unroll
        for (int j = 0; j < 2; j++) { accg[i][j] = (f32x4v)0.0f; accu[i][j] = (f32x4v)0.0f; }

    bf16x8 aR0 = *(const bf16x8*)aptr0;
    bf16x8 aR1 = *(const bf16x8*)aptr1;
    f32x4v g0 = *(const f32x4v*)(wg + boff);
    f32x4v g1 = *(const f32x4v*)(wg + boff + 4);
    f32x4v u0 = *(const f32x4v*)(wu + boff);
    f32x4v u1 = *(const f32x4v*)(wu + boff + 4);

    for (int k0 = 0; k0 < HH; k0 += 32) {
        bf16x8 bgv, buv;
        bgv[0] = (__bf16)g0[0]; bgv[1] = (__bf16)g0[1]; bgv[2] = (__bf16)g0[2]; bgv[3] = (__bf16)g0[3];
        bgv[4] = (__bf16)g1[0]; bgv[5] = (__bf16)g1[1]; bgv[6] = (__bf16)g1[2]; bgv[7] = (__bf16)g1[3];
        buv[0] = (__bf16)u0[0]; buv[1] = (__bf16)u0[1]; buv[2] = (__bf16)u0[2]; buv[3] = (__bf16)u0[3];
        buv[4] = (__bf16)u1[0]; buv[5] = (__bf16)u1[1]; buv[6] = (__bf16)u1[2]; buv[7] = (__bf16)u1[3];
        __syncthreads();
        *(bf16x8*)&As[arow0 * 32 + c8] = aR0;
        *(bf16x8*)&As[arow1 * 32 + c8] = aR1;
        *(bf16x8*)&Bg[brow * 32 + c8] = bgv;
        *(bf16x8*)&Bu[brow * 32 + c8] = buv;
        if (k0 + 32 < HH) {
            aR0 = *(const bf16x8*)(aptr0 + k0 + 32);
            aR1 = *(const bf16x8*)(aptr1 + k0 + 32);
            g0 = *(const f32x4v*)(wg + boff + k0 + 32);
            g1 = *(const f32x4v*)(wg + boff + k0 + 36);
            u0 = *(const f32x4v*)(wu + boff + k0 + 32);
            u1 = *(const f32x4v*)(wu + boff + k0 + 36);
        }
        __syncthreads();
        bf16x8 a[4];
#pragma unroll
        for (int i = 0; i < 4; i++)
            a[i] = *(const bf16x8*)&As[(wm * 64 + i * 16 + l16) * 32 + quad * 8];
#pragma unroll
        for (int j = 0; j < 2; j++) {
            bf16x8 bg = *(const bf16x8*)&Bg[(wn * 32 + j * 16 + l16) * 32 + quad * 8];
            bf16x8 bu = *(const bf16x8*)&Bu[(wn * 32 + j * 16 + l16) * 32 + quad * 8];
#pragma unroll
            for (int i = 0; i < 4; i++) {
                accg[i][j] = __builtin_amdgcn_mfma_f32_16x16x32_bf16(a[i], bg, accg[i][j], 0, 0, 0);
                accu[i][j] = __builtin_amdgcn_mfma_f32_16x16x32_bf16(a[i], bu, accu[i][j], 0, 0, 0);
            }
        }
    }
#pragma unroll
    for (int i = 0; i < 4; i++) {
        const int mrow = mt * 128 + wm * 64 + i * 16 + quad * 4;
#pragma unroll
        for (int r = 0; r < 4; r++) {
            const int slot = mrow + r;
            if (slot < ne) {
                __bf16* hrow = hbuf + (size_t)(base + slot) * II + nt * 64 + wn * 32 + l16;
#pragma unroll
                for (int j = 0; j < 2; j++) {
                    float g = accg[i][j][r], u = accu[i][j][r];
                    float sgl = g / (1.0f + __expf(-g));
                    hrow[j * 16] = (__bf16)(sgl * u);
                }
            }
        }
    }
}

__global__ __launch_bounds__(256, 3) void down_f32(
        const float* __restrict__ Wd, const float* __restrict__ Wds,
        const __bf16* __restrict__ hbuf, float* __restrict__ out,
        const int* __restrict__ nlist, const int* __restrict__ offs,
        const int* __restrict__ tlist, const float* __restrict__ wlist) {
    const int e = blockIdx.z;
    const int ne = nlist[e];
    const int bx = blockIdx.x;
    const int nt = bx & 7;
    const int mt = bx >> 3;
    if (mt * 128 >= ne) return;
    const int base = offs[e];
    const float* wd = (e < EE) ? Wd + (size_t)e * HH * II : Wds;

    __shared__ __bf16 As[128 * 32];
    __shared__ __bf16 Bs[128 * 32];

    const int tid = threadIdx.x;
    const int arow0 = tid >> 2, c8 = (tid & 3) * 8;
    const int arow1 = arow0 + 64;
    const int cl0 = min(mt * 128 + arow0, ne - 1);
    const int cl1 = min(mt * 128 + arow1, ne - 1);
    const __bf16* aptr0 = hbuf + (size_t)(base + cl0) * II + c8;
    const __bf16* aptr1 = hbuf + (size_t)(base + cl1) * II + c8;
    const size_t boff0 = (size_t)(nt * 128 + arow0) * II + c8;
    const size_t boff1 = (size_t)(nt * 128 + arow1) * II + c8;

    const int wid = tid >> 6, lane = tid & 63;
    const int wm = wid >> 1, wn = wid & 1;
    const int l16 = lane & 15, quad = lane >> 4;

    f32x4v acc[4][4];
#pragma unroll
    for (int i = 0; i < 4; i++)
#pragma unroll
        for (int j = 0; j < 4; j++) acc[i][j] = (f32x4v)0.0f;

    bf16x8 aR0 = *(const bf16x8*)aptr0;
    bf16x8 aR1 = *(const bf16x8*)aptr1;
    f32x4v b00 = *(const f32x4v*)(wd + boff0);
    f32x4v b01 = *(const f32x4v*)(wd + boff0 + 4);
    f32x4v b10 = *(const f32x4v*)(wd + boff1);
    f32x4v b11 = *(const f32x4v*)(wd + boff1 + 4);

    for (int k0 = 0; k0 < II; k0 += 32) {
        bf16x8 bs0, bs1;
        bs0[0] = (__bf16)b00[0]; bs0[1] = (__bf16)b00[1]; bs0[2] = (__bf16)b00[2]; bs0[3] = (__bf16)b00[3];
        bs0[4] = (__bf16)b01[0]; bs0[5] = (__bf16)b01[1]; bs0[6] = (__bf16)b01[2]; bs0[7] = (__bf16)b01[3];
        bs1[0] = (__bf16)b10[0]; bs1[1] = (__bf16)b10[1]; bs1[2] = (__bf16)b10[2]; bs1[3] = (__bf16)b10[3];
        bs1[4] = (__bf16)b11[0]; bs1[5] = (__bf16)b11[1]; bs1[6] = (__bf16)b11[2]; bs1[7] = (__bf16)b11[3];
        __syncthreads();
        *(bf16x8*)&As[arow0 * 32 + c8] = aR0;
        *(bf16x8*)&As[arow1 * 32 + c8] = aR1;
        *(bf16x8*)&Bs[arow0 * 32 + c8] = bs0;
        *(bf16x8*)&Bs[arow1 * 32 + c8] = bs1;
        if (k0 + 32 < II) {
            aR0 = *(const bf16x8*)(aptr0 + k0 + 32);
            aR1 = *(const bf16x8*)(aptr1 + k0 + 32);
            b00 = *(const f32x4v*)(wd + boff0 + k0 + 32);
            b01 = *(const f32x4v*)(wd + boff0 + k0 + 36);
            b10 = *(const f32x4v*)(wd + boff1 + k0 + 32);
            b11 = *(const f32x4v*)(wd + boff1 + k0 + 36);
        }
        __syncthreads();
        bf16x8 a[4];
#pragma unroll
        for (int i = 0; i < 4; i++)
            a[i] = *(const bf16x8*)&As[(wm * 64 + i * 16 + l16) * 32 + quad * 8];
#pragma unroll
        for (int j = 0; j < 4; j++) {
            bf16x8 b = *(const bf16x8*)&Bs[(wn * 64 + j * 16 + l16) * 32 + quad * 8];
#pragma unroll
            for (int i = 0; i < 4; i++)
                acc[i][j] = __builtin_amdgcn_mfma_f32_16x16x32_bf16(a[i], b, acc[i][j], 0, 0, 0);
        }
    }
#pragma unroll
    for (int i = 0; i < 4; i++) {
        const int mrow = mt * 128 + wm * 64 + i * 16 + quad * 4;
#pragma unroll
        for (int r = 0; r < 4; r++) {
            const int slot = mrow + r;
            if (slot < ne) {
                const int idx = base + slot;
                const int tok = tlist[idx];
                const float w = wlist[idx];
                float* orow = out + (size_t)tok * HH + nt * 128 + wn * 64 + l16;
#pragma unroll
                for (int j = 0; j < 4; j++)
                    atomicAdd(&orow[j * 16], w * acc[i][j][r]);
            }
        }
    }
}

// ---------------------------------------------------------------- launch
extern "C" void kernel_launch(void* const* d_in, const int* in_sizes, int n_in,
                              void* d_out, int out_size, void* d_ws, size_t ws_size,
                              hipStream_t stream) {
    const float* x   = (const float*)d_in[0];
    const float* Wgs = (const float*)d_in[1];
    const float* Wus = (const float*)d_in[2];
    const float* Wds = (const float*)d_in[3];
    const float* Wg  = (const float*)d_in[4];
    const float* Wu  = (const float*)d_in[5];
    const float* Wd  = (const float*)d_in[6];
    const float* Wr  = (const float*)d_in[7];
    float* out = (float*)d_out;                        // [NTOK][HH]
    float* logits = out + (size_t)NTOK * HH;           // [NTOK][EE]

    const size_t HB  = (size_t)NSLOT * II * 2;         // hbuf bf16
    const size_t XB  = (size_t)NTOK * HH * 2;          // xb bf16
    const size_t WEB = (size_t)EE * II * HH * 2;       // one routed weight set, bf16
    const size_t WSB = (size_t)II * HH * 2;            // one shared weight set, bf16
    const size_t META = 262144;
    const size_t needFast = HB + XB + 3 * WEB + 3 * WSB + META;   // ~216 MB

    char* ws = (char*)d_ws;

    if (ws_size >= needFast) {
        // -------- fast path: bf16 weights + global_load_lds GEMMs
        __bf16* hbuf = (__bf16*)ws;
        __bf16* xb   = (__bf16*)(ws + HB);
        __bf16* wgb  = (__bf16*)(ws + HB + XB);
        __bf16* wub  = (__bf16*)(ws + HB + XB + WEB);
        __bf16* wdb  = (__bf16*)(ws + HB + XB + 2 * WEB);
        __bf16* wgsb = (__bf16*)(ws + HB + XB + 3 * WEB);
        __bf16* wusb = (__bf16*)(ws + HB + XB + 3 * WEB + WSB);
        __bf16* wdsb = (__bf16*)(ws + HB + XB + 3 * WEB + 2 * WSB);
        char* meta   = ws + HB + XB + 3 * WEB + 3 * WSB;
        int* counts = (int*)meta;
        int* cursor = counts + 8;
        int* nlist  = cursor + 8;
        int* offs   = nlist + 8;
        int* sel    = offs + 8;
        int* tlist  = sel + 2 * NTOK;
        float* wtop = (float*)(tlist + NSLOT);
        float* wlist = wtop + 2 * NTOK;

        hipMemsetAsync(counts, 0, 8 * sizeof(int), stream);
        hipMemsetAsync(out, 0, (size_t)NTOK * HH * sizeof(float), stream);

        cvt_x<<<1024, 256, 0, stream>>>(x, xb);
        cvt_w6<<<dim3(1024, 6), 256, 0, stream>>>(Wg, Wu, Wd, Wgs, Wus, Wds,
                                                  wgb, wub, wdb, wgsb, wusb, wdsb);
        router_k<<<NTOK / 4, 256, 0, stream>>>(x, Wr, logits, counts, sel, wtop, tlist, wlist);
        finalize_k<<<1, 64, 0, stream>>>(counts, cursor, nlist, offs);
        scatter_k<<<NTOK / 256, 256, 0, stream>>>(sel, wtop, cursor, tlist, wlist);
        gateup_bf<<<dim3(1536, 1, EE + 1), 256, 0, stream>>>(wgb, wub, wgsb, wusb, xb, hbuf,
                                                             nlist, offs, tlist);
        down_bf<<<dim3(256, 1, EE + 1), 256, 0, stream>>>(wdb, wdsb, hbuf, out,
                                                          nlist, offs, tlist, wlist);
    } else {
        // -------- fallback: previous verified path (~78 MB workspace)
        __bf16* hbuf = (__bf16*)ws;
        __bf16* xb   = (__bf16*)(ws + HB);
        char* meta   = ws + HB + XB;
        int* counts = (int*)meta;
        int* cursor = counts + 8;
        int* nlist  = cursor + 8;
        int* offs   = nlist + 8;
        int* sel    = offs + 8;
        int* tlist  = sel + 2 * NTOK;
        float* wtop = (float*)(tlist + NSLOT);
        float* wlist = wtop + 2 * NTOK;

        hipMemsetAsync(counts, 0, 8 * sizeof(int), stream);
        hipMemsetAsync(out, 0, (size_t)NTOK * HH * sizeof(float), stream);

        cvt_x<<<1024, 256, 0, stream>>>(x, xb);
        router_k<<<NTOK / 4, 256, 0, stream>>>(x, Wr, logits, counts, sel, wtop, tlist, wlist);
        finalize_k<<<1, 64, 0, stream>>>(counts, cursor, nlist, offs);
        scatter_k<<<NTOK / 256, 256, 0, stream>>>(sel, wtop, cursor, tlist, wlist);
        gateup_f32<<<dim3(1536, 1, EE + 1), 256, 0, stream>>>(Wg, Wu, Wgs, Wus, xb, hbuf,
                                                              nlist, offs, tlist);
        down_f32<<<dim3(256, 1, EE + 1), 256, 0, stream>>>(Wd, Wds, hbuf, out,
                                                           nlist, offs, tlist, wlist);
    }
}

// Round 2
// 770.916 us; speedup vs baseline: 1.0650x; 1.0028x over previous
//
#include <hip/hip_runtime.h>
#include <hip/hip_bf16.h>

// Problem constants (B=2,S=2048,H=1024,I=2816,E=7,TOPK=2)
#define NTOK 4096         // B*S
#define HH 1024
#define II 2816
#define EE 7
#define SHARED_BASE 8192  // NTOK*TOPK routed slots, then NTOK shared slots
#define NSLOT 12288       // 8192 + 4096

typedef __bf16 bf16x8 __attribute__((ext_vector_type(8)));
typedef __bf16 bf16x4 __attribute__((ext_vector_type(4)));
typedef float  f32x4v __attribute__((ext_vector_type(4)));

// global->LDS direct DMA, 16B per lane. LDS dest must be linear in lane order
// (wave-uniform base + lane*16); global src may be fully per-lane.
typedef const __attribute__((address_space(1))) void* gas_ptr;
typedef __attribute__((address_space(3))) void* las_ptr;
__device__ __forceinline__ void load16_lds(const void* g, void* l) {
    __builtin_amdgcn_global_load_lds((gas_ptr)g, (las_ptr)l, 16, 0, 0);
}

// ---------------------------------------------------------------- cvt x->bf16
__global__ void cvt_x(const float* __restrict__ x, __bf16* __restrict__ xb) {
    int i = blockIdx.x * blockDim.x + threadIdx.x;   // 262144 threads
    const f32x4v* xv = (const f32x4v*)x;
    bf16x4* ov = (bf16x4*)xb;
    int base = i * 4;                                 // 4 float4 per thread
#pragma unroll
    for (int j = 0; j < 4; j++) {
        f32x4v f = xv[base + j];
        bf16x4 b;
        b[0] = (__bf16)f[0]; b[1] = (__bf16)f[1];
        b[2] = (__bf16)f[2]; b[3] = (__bf16)f[3];
        ov[base + j] = b;
    }
}

// ---------------------------------------------------------------- cvt weights
// y=0/1: routed Wg/Wu -> Wgu interleaved (16-row groups: [g16|u16|g16|u16...])
// y=2/3: shared Wgs/Wus -> Wgus interleaved
// y=4/5: routed/shared Wd -> bf16 linear
// Interleave map: gate row i -> combined row (i>>4)*32 + (i&15);  up: +16.
__global__ void cvt_w6(const float* __restrict__ Wg, const float* __restrict__ Wu,
                       const float* __restrict__ Wgs, const float* __restrict__ Wus,
                       const float* __restrict__ Wd, const float* __restrict__ Wds,
                       __bf16* __restrict__ wgu, __bf16* __restrict__ wgus,
                       __bf16* __restrict__ wdb, __bf16* __restrict__ wdsb) {
    const int y = blockIdx.y;
    const int H4 = HH / 4;                       // 256
    const int stride = gridDim.x * blockDim.x;
    int idx0 = blockIdx.x * blockDim.x + threadIdx.x;
    if (y < 2) {
        const f32x4v* sv = (const f32x4v*)(y == 0 ? Wg : Wu);
        const int add = y * 16;
        const int n4 = EE * II * H4;
        for (int idx = idx0; idx < n4; idx += stride) {
            int h4 = idx & (H4 - 1);
            int row = idx >> 8;                  // e*II + i
            int e = row / II, i = row - e * II;
            int crow = e * 2 * II + ((i >> 4) * 32) + (i & 15) + add;
            f32x4v f = sv[idx];
            bf16x4 b;
            b[0] = (__bf16)f[0]; b[1] = (__bf16)f[1];
            b[2] = (__bf16)f[2]; b[3] = (__bf16)f[3];
            ((bf16x4*)wgu)[crow * H4 + h4] = b;
        }
    } else if (y < 4) {
        const f32x4v* sv = (const f32x4v*)(y == 2 ? Wgs : Wus);
        const int add = (y - 2) * 16;
        const int n4 = II * H4;
        for (int idx = idx0; idx < n4; idx += stride) {
            int h4 = idx & (H4 - 1);
            int i = idx >> 8;
            int crow = ((i >> 4) * 32) + (i & 15) + add;
            f32x4v f = sv[idx];
            bf16x4 b;
            b[0] = (__bf16)f[0]; b[1] = (__bf16)f[1];
            b[2] = (__bf16)f[2]; b[3] = (__bf16)f[3];
            ((bf16x4*)wgus)[crow * H4 + h4] = b;
        }
    } else {
        const f32x4v* sv = (const f32x4v*)(y == 4 ? Wd : Wds);
        bf16x4* dv = (bf16x4*)(y == 4 ? wdb : wdsb);
        const int n4 = (y == 4 ? EE : 1) * HH * II / 4;
        for (int idx = idx0; idx < n4; idx += stride) {
            f32x4v f = sv[idx];
            bf16x4 b;
            b[0] = (__bf16)f[0]; b[1] = (__bf16)f[1];
            b[2] = (__bf16)f[2]; b[3] = (__bf16)f[3];
            dv[idx] = b;
        }
    }
}

// ---------------------------------------------------------------- router
// One wave per token. fp64 accumulation so top-2 selection matches the
// reference even near ties.
__global__ void router_k(const float* __restrict__ x, const float* __restrict__ Wr,
                         float* __restrict__ logits, int* __restrict__ counts,
                         int* __restrict__ sel, float* __restrict__ wtop,
                         int* __restrict__ tlist, float* __restrict__ wlist) {
    int wave = threadIdx.x >> 6;
    int lane = threadIdx.x & 63;
    int t = blockIdx.x * 4 + wave;
    const float* xr = x + (size_t)t * HH;
    double acc[EE];
#pragma unroll
    for (int e = 0; e < EE; e++) acc[e] = 0.0;
    for (int j = 0; j < 16; j++) {
        int h = lane + j * 64;
        double xv = (double)xr[h];
#pragma unroll
        for (int e = 0; e < EE; e++) acc[e] += xv * (double)Wr[e * HH + h];
    }
#pragma unroll
    for (int e = 0; e < EE; e++) {
        for (int off = 32; off > 0; off >>= 1) acc[e] += __shfl_down(acc[e], off, 64);
    }
    if (lane == 0) {
        int e0 = 0;
        for (int e = 1; e < EE; e++) if (acc[e] > acc[e0]) e0 = e;
        int e1 = -1;
        for (int e = 0; e < EE; e++) {
            if (e == e0) continue;
            if (e1 < 0 || acc[e] > acc[e1]) e1 = e;
        }
        double w1 = exp(acc[e1] - acc[e0]);
        double s = 1.0 + w1;
        for (int e = 0; e < EE; e++) logits[(size_t)t * EE + e] = (float)acc[e];
        sel[2 * t] = e0; sel[2 * t + 1] = e1;
        wtop[2 * t] = (float)(1.0 / s); wtop[2 * t + 1] = (float)(w1 / s);
        atomicAdd(&counts[e0], 1);
        atomicAdd(&counts[e1], 1);
        tlist[SHARED_BASE + t] = t;
        wlist[SHARED_BASE + t] = 1.0f;
    }
}

// ---------------------------------------------------------------- finalize
__global__ void finalize_k(const int* __restrict__ counts, int* __restrict__ cursor,
                           int* __restrict__ nlist, int* __restrict__ offs) {
    if (threadIdx.x == 0 && blockIdx.x == 0) {
        int o = 0;
        for (int e = 0; e < EE; e++) {
            offs[e] = o; cursor[e] = o; nlist[e] = counts[e];
            o += counts[e];
        }
        offs[EE] = SHARED_BASE;
        nlist[EE] = NTOK;
        cursor[EE] = SHARED_BASE;
    }
}

// ---------------------------------------------------------------- scatter
// Also records the inverse map slot-of-(token,j) for the combine kernel.
__global__ void scatter_k(const int* __restrict__ sel, const float* __restrict__ wtop,
                          int* __restrict__ cursor, int* __restrict__ tlist,
                          float* __restrict__ wlist, int* __restrict__ inv) {
    int t = blockIdx.x * blockDim.x + threadIdx.x;
    if (t >= NTOK) return;
#pragma unroll
    for (int j = 0; j < 2; j++) {
        int e = sel[2 * t + j];
        int slot = atomicAdd(&cursor[e], 1);
        tlist[slot] = t;
        wlist[slot] = wtop[2 * t + j];
        inv[2 * t + j] = slot;
    }
}

// ---------------------------------------------------------------- gate+up GEMM
// Fused: B = interleaved Wgu, so this is a plain 128(M)x128(N) BK=32 GEMM
// (m97 structure: 64 MFMA per 16 KB staged). Wave (wm,wn) covers combined
// cols wn*64 + j*16; j even = gate, j odd = up of real col group j>>1.
// global_load_lds staging; src-side XOR chunk swizzle + same XOR on ds_read.
// XCD swizzle: panel nt pinned to XCD nt%8.
__global__ __launch_bounds__(256, 3) void gateup_gu(
        const __bf16* __restrict__ Wgu, const __bf16* __restrict__ Wgus,
        const __bf16* __restrict__ xb, __bf16* __restrict__ hbuf,
        const int* __restrict__ nlist, const int* __restrict__ offs,
        const int* __restrict__ tlist) {
    const int e = blockIdx.z;
    const int ne = nlist[e];
    const int bx = blockIdx.x;                 // 1536 per expert (48 nt' x 32 mt)
    const int nt = (bx & 7) + 8 * (bx >> 8);   // XCD = nt % 8
    const int mt = (bx >> 3) & 31;
    if (nt >= (2 * II) / 128) return;          // 44 real panels
    if (mt * 128 >= ne) return;
    const int base = offs[e];
    const __bf16* w = (e < EE) ? Wgu + (size_t)e * 2 * II * HH : Wgus;

    __shared__ __bf16 As[128 * 32];   // 8 KB
    __shared__ __bf16 Bs[128 * 32];   // 8 KB

    const int tid = threadIdx.x;
    const int r0 = tid >> 2;                   // row 0..63 (also row+64)
    const int c  = tid & 3;                    // 16B chunk 0..3
    const int cs = (c ^ ((r0 >> 1) & 3)) * 8;  // swizzled source chunk (elems)
    const int cl0 = min(mt * 128 + r0, ne - 1);
    const int cl1 = min(mt * 128 + r0 + 64, ne - 1);
    const __bf16* aptr0 = xb + (size_t)tlist[base + cl0] * HH + cs;
    const __bf16* aptr1 = xb + (size_t)tlist[base + cl1] * HH + cs;
    const __bf16* bptr0 = w + (size_t)(nt * 128 + r0) * HH + cs;
    const __bf16* bptr1 = w + (size_t)(nt * 128 + r0 + 64) * HH + cs;
    __bf16* ldsA0 = &As[tid * 8];              // linear lane order, 16B/lane
    __bf16* ldsA1 = &As[64 * 32 + tid * 8];
    __bf16* ldsB0 = &Bs[tid * 8];
    __bf16* ldsB1 = &Bs[64 * 32 + tid * 8];

    const int wid = tid >> 6, lane = tid & 63;
    const int wm = wid >> 1, wn = wid & 1;
    const int l16 = lane & 15, quad = lane >> 4;
    const int qsw = (quad ^ ((l16 >> 1) & 3)) * 8;   // read-side swizzle (elems)

    f32x4v acc[4][4];
#pragma unroll
    for (int i = 0; i < 4; i++)
#pragma unroll
        for (int j = 0; j < 4; j++) acc[i][j] = (f32x4v)0.0f;

    for (int k0 = 0; k0 < HH; k0 += 32) {
        __syncthreads();                       // prev MFMA reads done
        load16_lds(aptr0 + k0, ldsA0);
        load16_lds(aptr1 + k0, ldsA1);
        load16_lds(bptr0 + k0, ldsB0);
        load16_lds(bptr1 + k0, ldsB1);
        __syncthreads();                       // vmcnt drained before barrier
        bf16x8 a[4];
#pragma unroll
        for (int i = 0; i < 4; i++)
            a[i] = *(const bf16x8*)&As[(wm * 64 + i * 16 + l16) * 32 + qsw];
#pragma unroll
        for (int j = 0; j < 4; j++) {
            bf16x8 b = *(const bf16x8*)&Bs[(wn * 64 + j * 16 + l16) * 32 + qsw];
#pragma unroll
            for (int i = 0; i < 4; i++)
                acc[i][j] = __builtin_amdgcn_mfma_f32_16x16x32_bf16(a[i], b, acc[i][j], 0, 0, 0);
        }
    }
    // epilogue: j=2*jj is gate, j=2*jj+1 is up, real col = nt*64+wn*32+jj*16+l16
#pragma unroll
    for (int i = 0; i < 4; i++) {
        const int mrow = mt * 128 + wm * 64 + i * 16 + quad * 4;
#pragma unroll
        for (int r = 0; r < 4; r++) {
            const int slot = mrow + r;
            if (slot < ne) {
                __bf16* hrow = hbuf + (size_t)(base + slot) * II + nt * 64 + wn * 32 + l16;
#pragma unroll
                for (int jj = 0; jj < 2; jj++) {
                    float g = acc[i][2 * jj][r], u = acc[i][2 * jj + 1][r];
                    float sgl = g / (1.0f + __expf(-g));
                    hrow[jj * 16] = (__bf16)(sgl * u);
                }
            }
        }
    }
}

// ---------------------------------------------------------------- down proj
// 128(M)x128(N), BK=32, wave tile 64x64. Plain stores of w*acc into ybuf
// (one writer per cell) — no atomics. Same staging/swizzle as gateup.
__global__ __launch_bounds__(256, 3) void down_y(
        const __bf16* __restrict__ Wd, const __bf16* __restrict__ Wds,
        const __bf16* __restrict__ hbuf, float* __restrict__ ybuf,
        const int* __restrict__ nlist, const int* __restrict__ offs,
        const int* __restrict__ tlist, const float* __restrict__ wlist) {
    const int e = blockIdx.z;
    const int ne = nlist[e];
    const int bx = blockIdx.x;                 // [0,256): 8 nt x 32 mt
    const int nt = bx & 7;                     // XCD = nt
    const int mt = bx >> 3;
    if (mt * 128 >= ne) return;
    const int base = offs[e];
    const __bf16* wd = (e < EE) ? Wd + (size_t)e * HH * II : Wds;

    __shared__ __bf16 As[128 * 32];   // 8 KB
    __shared__ __bf16 Bs[128 * 32];   // 8 KB

    const int tid = threadIdx.x;
    const int r0 = tid >> 2;
    const int c  = tid & 3;
    const int cs = (c ^ ((r0 >> 1) & 3)) * 8;
    const int cl0 = min(mt * 128 + r0, ne - 1);
    const int cl1 = min(mt * 128 + r0 + 64, ne - 1);
    const __bf16* aptr0 = hbuf + (size_t)(base + cl0) * II + cs;
    const __bf16* aptr1 = hbuf + (size_t)(base + cl1) * II + cs;
    const __bf16* bptr0 = wd + (size_t)(nt * 128 + r0) * II + cs;
    const __bf16* bptr1 = wd + (size_t)(nt * 128 + r0 + 64) * II + cs;
    __bf16* ldsA0 = &As[tid * 8];
    __bf16* ldsA1 = &As[64 * 32 + tid * 8];
    __bf16* ldsB0 = &Bs[tid * 8];
    __bf16* ldsB1 = &Bs[64 * 32 + tid * 8];

    const int wid = tid >> 6, lane = tid & 63;
    const int wm = wid >> 1, wn = wid & 1;
    const int l16 = lane & 15, quad = lane >> 4;
    const int qsw = (quad ^ ((l16 >> 1) & 3)) * 8;

    f32x4v acc[4][4];
#pragma unroll
    for (int i = 0; i < 4; i++)
#pragma unroll
        for (int j = 0; j < 4; j++) acc[i][j] = (f32x4v)0.0f;

    for (int k0 = 0; k0 < II; k0 += 32) {
        __syncthreads();
        load16_lds(aptr0 + k0, ldsA0);
        load16_lds(aptr1 + k0, ldsA1);
        load16_lds(bptr0 + k0, ldsB0);
        load16_lds(bptr1 + k0, ldsB1);
        __syncthreads();
        bf16x8 a[4];
#pragma unroll
        for (int i = 0; i < 4; i++)
            a[i] = *(const bf16x8*)&As[(wm * 64 + i * 16 + l16) * 32 + qsw];
#pragma unroll
        for (int j = 0; j < 4; j++) {
            bf16x8 b = *(const bf16x8*)&Bs[(wn * 64 + j * 16 + l16) * 32 + qsw];
#pragma unroll
            for (int i = 0; i < 4; i++)
                acc[i][j] = __builtin_amdgcn_mfma_f32_16x16x32_bf16(a[i], b, acc[i][j], 0, 0, 0);
        }
    }
    // epilogue: ybuf[slot] = w_slot * acc (exactly one writer per cell)
#pragma unroll
    for (int i = 0; i < 4; i++) {
        const int mrow = mt * 128 + wm * 64 + i * 16 + quad * 4;
#pragma unroll
        for (int r = 0; r < 4; r++) {
            const int slot = mrow + r;
            if (slot < ne) {
                const int idx = base + slot;
                const float w = wlist[idx];
                float* orow = ybuf + (size_t)idx * HH + nt * 128 + wn * 64 + l16;
#pragma unroll
                for (int j = 0; j < 4; j++)
                    orow[j * 16] = w * acc[i][j][r];
            }
        }
    }
}

// ---------------------------------------------------------------- combine
// out[t] = ybuf[slot0(t)] + ybuf[slot1(t)] + ybuf[SHARED_BASE + t]
__global__ void combine_k(const float* __restrict__ ybuf, const int* __restrict__ inv,
                          float* __restrict__ out) {
    int idx = blockIdx.x * blockDim.x + threadIdx.x;   // NTOK*256 threads
    int t = idx >> 8, h4 = idx & 255;
    const f32x4v* y0 = (const f32x4v*)(ybuf + (size_t)inv[2 * t] * HH);
    const f32x4v* y1 = (const f32x4v*)(ybuf + (size_t)inv[2 * t + 1] * HH);
    const f32x4v* ys = (const f32x4v*)(ybuf + (size_t)(SHARED_BASE + t) * HH);
    f32x4v r = y0[h4] + y1[h4] + ys[h4];
    ((f32x4v*)(out + (size_t)t * HH))[h4] = r;
}

// ---------------------------------------------------------------- launch
extern "C" void kernel_launch(void* const* d_in, const int* in_sizes, int n_in,
                              void* d_out, int out_size, void* d_ws, size_t ws_size,
                              hipStream_t stream) {
    const float* x   = (const float*)d_in[0];
    const float* Wgs = (const float*)d_in[1];
    const float* Wus = (const float*)d_in[2];
    const float* Wds = (const float*)d_in[3];
    const float* Wg  = (const float*)d_in[4];
    const float* Wu  = (const float*)d_in[5];
    const float* Wd  = (const float*)d_in[6];
    const float* Wr  = (const float*)d_in[7];
    float* out = (float*)d_out;                        // [NTOK][HH]
    float* logits = out + (size_t)NTOK * HH;           // [NTOK][EE]

    // workspace layout (~216 MB, same footprint as previous round):
    //   hbuf | xb | wgu (2*WEB) | wdb (WEB) | wgus (2*WSB) | wdsb (WSB) | meta
    // ybuf (50.3 MB fp32) ALIASES wgu (80.7 MB): wgu is dead once gateup_gu
    // completes; down_y runs strictly after it on the stream.
    const size_t HB  = (size_t)NSLOT * II * 2;         // hbuf bf16
    const size_t XB  = (size_t)NTOK * HH * 2;          // xb bf16
    const size_t WEB = (size_t)EE * II * HH * 2;       // one routed weight set, bf16
    const size_t WSB = (size_t)II * HH * 2;            // one shared weight set, bf16

    char* ws = (char*)d_ws;
    __bf16* hbuf = (__bf16*)ws;
    __bf16* xb   = (__bf16*)(ws + HB);
    __bf16* wgu  = (__bf16*)(ws + HB + XB);
    float*  ybuf = (float*)wgu;                        // alias (see above)
    __bf16* wdb  = (__bf16*)(ws + HB + XB + 2 * WEB);
    __bf16* wgus = (__bf16*)(ws + HB + XB + 3 * WEB);
    __bf16* wdsb = (__bf16*)(ws + HB + XB + 3 * WEB + 2 * WSB);
    char* meta   = ws + HB + XB + 3 * WEB + 3 * WSB;
    int* counts = (int*)meta;            // 8
    int* cursor = counts + 8;            // 8
    int* nlist  = cursor + 8;            // 8
    int* offs   = nlist + 8;             // 8
    int* sel    = offs + 8;              // 2*NTOK
    int* tlist  = sel + 2 * NTOK;        // NSLOT
    float* wtop = (float*)(tlist + NSLOT);   // 2*NTOK
    float* wlist = wtop + 2 * NTOK;          // NSLOT
    int* inv    = (int*)(wlist + NSLOT);     // 2*NTOK

    hipMemsetAsync(counts, 0, 8 * sizeof(int), stream);

    cvt_x<<<1024, 256, 0, stream>>>(x, xb);
    cvt_w6<<<dim3(1024, 6), 256, 0, stream>>>(Wg, Wu, Wgs, Wus, Wd, Wds,
                                              wgu, wgus, wdb, wdsb);
    router_k<<<NTOK / 4, 256, 0, stream>>>(x, Wr, logits, counts, sel, wtop, tlist, wlist);
    finalize_k<<<1, 64, 0, stream>>>(counts, cursor, nlist, offs);
    scatter_k<<<NTOK / 256, 256, 0, stream>>>(sel, wtop, cursor, tlist, wlist, inv);
    gateup_gu<<<dim3(1536, 1, EE + 1), 256, 0, stream>>>(wgu, wgus, xb, hbuf,
                                                         nlist, offs, tlist);
    down_y<<<dim3(256, 1, EE + 1), 256, 0, stream>>>(wdb, wdsb, hbuf, ybuf,
                                                     nlist, offs, tlist, wlist);
    combine_k<<<NTOK, 256, 0, stream>>>(ybuf, inv, out);
}

// Round 3
// 717.006 us; speedup vs baseline: 1.1450x; 1.0752x over previous
//
#include <hip/hip_runtime.h>
#include <hip/hip_bf16.h>

// Problem constants (B=2,S=2048,H=1024,I=2816,E=7,TOPK=2)
#define NTOK 4096         // B*S
#define HH 1024
#define II 2816
#define EE 7
#define SHARED_BASE 8192  // NTOK*TOPK routed slots, then NTOK shared slots
#define NSLOT 12288       // 8192 + 4096

typedef __bf16 bf16x8 __attribute__((ext_vector_type(8)));
typedef __bf16 bf16x4 __attribute__((ext_vector_type(4)));
typedef float  f32x4v __attribute__((ext_vector_type(4)));

// global->LDS direct DMA, 16B per lane. LDS dest must be linear in lane order
// (wave-uniform base + lane*16); global src may be fully per-lane.
typedef const __attribute__((address_space(1))) void* gas_ptr;
typedef __attribute__((address_space(3))) void* las_ptr;
__device__ __forceinline__ void load16_lds(const void* g, void* l) {
    __builtin_amdgcn_global_load_lds((gas_ptr)g, (las_ptr)l, 16, 0, 0);
}

#define VMCNT(n) asm volatile("s_waitcnt vmcnt(" #n ")" ::: "memory")
#define LGKM0    asm volatile("s_waitcnt lgkmcnt(0)" ::: "memory")

__device__ __forceinline__ bf16x8 cvt8(f32x4v f0, f32x4v f1) {
    bf16x8 b;
    b[0] = (__bf16)f0[0]; b[1] = (__bf16)f0[1]; b[2] = (__bf16)f0[2]; b[3] = (__bf16)f0[3];
    b[4] = (__bf16)f1[0]; b[5] = (__bf16)f1[1]; b[6] = (__bf16)f1[2]; b[7] = (__bf16)f1[3];
    return b;
}

// ---------------------------------------------------------------- prep
// One launch, blockIdx.y roles (all independent, read-only on inputs):
//  y=0: router (fp64 accum, top-2 + softmax weights)
//  y=1: x -> xb bf16
//  y=2/3: Wg/Wu -> wgu interleaved 16-row groups [g16|u16|...] per expert
//  y=4/5: Wgs/Wus -> wgus interleaved
//  y=6/7: Wd/Wds -> bf16 linear
// Interleave map: gate row i -> combined row (i>>4)*32 + (i&15); up: +16.
__global__ void prep_k(const float* __restrict__ x, const float* __restrict__ Wr,
                       const float* __restrict__ Wg, const float* __restrict__ Wu,
                       const float* __restrict__ Wgs, const float* __restrict__ Wus,
                       const float* __restrict__ Wd, const float* __restrict__ Wds,
                       __bf16* __restrict__ xb, __bf16* __restrict__ wgu,
                       __bf16* __restrict__ wgus, __bf16* __restrict__ wdb,
                       __bf16* __restrict__ wdsb,
                       float* __restrict__ logits, int* __restrict__ counts,
                       int* __restrict__ sel, float* __restrict__ wtop,
                       int* __restrict__ tlist, float* __restrict__ wlist) {
    const int y = blockIdx.y;
    const int tid = threadIdx.x;
    const int stride = gridDim.x * blockDim.x;          // 262144
    int idx0 = blockIdx.x * blockDim.x + tid;

    if (y == 0) {
        // ---- router: one wave per token
        int wave = tid >> 6, lane = tid & 63;
        int t = blockIdx.x * 4 + wave;
        const float* xr = x + (size_t)t * HH;
        double acc[EE];
#pragma unroll
        for (int e = 0; e < EE; e++) acc[e] = 0.0;
        for (int j = 0; j < 16; j++) {
            int h = lane + j * 64;
            double xv = (double)xr[h];
#pragma unroll
            for (int e = 0; e < EE; e++) acc[e] += xv * (double)Wr[e * HH + h];
        }
#pragma unroll
        for (int e = 0; e < EE; e++) {
            for (int off = 32; off > 0; off >>= 1) acc[e] += __shfl_down(acc[e], off, 64);
        }
        if (lane == 0) {
            int e0 = 0;
            for (int e = 1; e < EE; e++) if (acc[e] > acc[e0]) e0 = e;
            int e1 = -1;
            for (int e = 0; e < EE; e++) {
                if (e == e0) continue;
                if (e1 < 0 || acc[e] > acc[e1]) e1 = e;
            }
            double w1 = exp(acc[e1] - acc[e0]);
            double s = 1.0 + w1;
            for (int e = 0; e < EE; e++) logits[(size_t)t * EE + e] = (float)acc[e];
            sel[2 * t] = e0; sel[2 * t + 1] = e1;
            wtop[2 * t] = (float)(1.0 / s); wtop[2 * t + 1] = (float)(w1 / s);
            atomicAdd(&counts[e0], 1);
            atomicAdd(&counts[e1], 1);
            tlist[SHARED_BASE + t] = t;
            wlist[SHARED_BASE + t] = 1.0f;
        }
    } else if (y == 1) {
        // ---- x -> bf16 (16 floats / thread)
        const f32x4v* xv = (const f32x4v*)x;
        bf16x8* ov = (bf16x8*)xb;
        int n8 = NTOK * HH / 8;                       // 524288
        for (int i = idx0; i < n8; i += stride)
            ov[i] = cvt8(xv[2 * i], xv[2 * i + 1]);
    } else if (y <= 3) {
        // ---- routed gate/up -> interleaved wgu
        const f32x4v* sv = (const f32x4v*)(y == 2 ? Wg : Wu);
        const int add = (y - 2) * 16;
        const int n8 = EE * II * (HH / 8);
        for (int idx = idx0; idx < n8; idx += stride) {
            int h8 = idx & 127, row = idx >> 7;       // row = e*II + i
            int e2 = row / II, i2 = row - e2 * II;
            int crow = e2 * 2 * II + (i2 >> 4) * 32 + (i2 & 15) + add;
            bf16x8 b = cvt8(sv[row * 256 + h8 * 2], sv[row * 256 + h8 * 2 + 1]);
            *(bf16x8*)&wgu[(size_t)crow * HH + h8 * 8] = b;
        }
    } else if (y <= 5) {
        // ---- shared gate/up -> interleaved wgus
        const f32x4v* sv = (const f32x4v*)(y == 4 ? Wgs : Wus);
        const int add = (y - 4) * 16;
        const int n8 = II * (HH / 8);
        for (int idx = idx0; idx < n8; idx += stride) {
            int h8 = idx & 127, i2 = idx >> 7;
            int crow = (i2 >> 4) * 32 + (i2 & 15) + add;
            bf16x8 b = cvt8(sv[i2 * 256 + h8 * 2], sv[i2 * 256 + h8 * 2 + 1]);
            *(bf16x8*)&wgus[(size_t)crow * HH + h8 * 8] = b;
        }
    } else {
        // ---- down weights -> bf16 linear
        const f32x4v* sv = (const f32x4v*)(y == 6 ? Wd : Wds);
        bf16x8* dv = (bf16x8*)(y == 6 ? wdb : wdsb);
        const int n8 = (y == 6 ? EE : 1) * HH * (II / 8);
        for (int idx = idx0; idx < n8; idx += stride)
            dv[idx] = cvt8(sv[2 * idx], sv[2 * idx + 1]);
    }
}

// ---------------------------------------------------------------- finalize
__global__ void finalize_k(const int* __restrict__ counts, int* __restrict__ cursor,
                           int* __restrict__ nlist, int* __restrict__ offs) {
    if (threadIdx.x == 0 && blockIdx.x == 0) {
        int o = 0;
        for (int e = 0; e < EE; e++) {
            offs[e] = o; cursor[e] = o; nlist[e] = counts[e];
            o += counts[e];
        }
        offs[EE] = SHARED_BASE;
        nlist[EE] = NTOK;
        cursor[EE] = SHARED_BASE;
    }
}

// ---------------------------------------------------------------- scatter
__global__ void scatter_k(const int* __restrict__ sel, const float* __restrict__ wtop,
                          int* __restrict__ cursor, int* __restrict__ tlist,
                          float* __restrict__ wlist, int* __restrict__ inv) {
    int t = blockIdx.x * blockDim.x + threadIdx.x;
    if (t >= NTOK) return;
#pragma unroll
    for (int j = 0; j < 2; j++) {
        int e = sel[2 * t + j];
        int slot = atomicAdd(&cursor[e], 1);
        tlist[slot] = t;
        wlist[slot] = wtop[2 * t + j];
        inv[2 * t + j] = slot;
    }
}

// ---------------------------------------------------------------- gate+up GEMM
// 256(M-slots) x 256(N-combined) tile, BK=64, 8 waves (2M x 4N), wave tile
// 128x64, double-buffered 128 KB LDS, 1 block/CU.
// Pipeline per K-tile t: stage tile t+1 (8 global_load_lds dwordx4/thread),
// s_waitcnt vmcnt(8)  [tile t landed; t+1 stays IN FLIGHT across the barrier],
// s_barrier, 64 MFMA/wave, lgkmcnt(0)+sched_barrier (reads drained before the
// closing barrier -> next stage may overwrite), s_barrier.
// Ledger: in-flight enters at 8 (tile t), +8 issue = 16, vmcnt(8) retires
// exactly tile t. Never drains to 0 in the main loop (T4).
// Swizzle: source chunk ck^(row&7) at 16B granularity; identical XOR on the
// ds_read chunk -> 2-way residual bank aliasing (free).
__global__ __launch_bounds__(512, 1) void gugemm(
        const __bf16* __restrict__ Wgu, const __bf16* __restrict__ Wgus,
        const __bf16* __restrict__ xb, __bf16* __restrict__ hbuf,
        const int* __restrict__ nlist, const int* __restrict__ offs,
        const int* __restrict__ tlist) {
    const int e = blockIdx.z;
    const int ne = nlist[e];
    const int nt = blockIdx.x % 22;            // 22 N-panels of 256 combined
    const int mt = blockIdx.x / 22;            // up to 16 M-tiles of 256 slots
    if (mt * 256 >= ne) return;
    const int base = offs[e];
    const __bf16* w = (e < EE) ? Wgu + (size_t)e * 2 * II * HH : Wgus;

    __shared__ __bf16 sm[2][2][256 * 64];      // [buf][A|B][row*64+..] 128 KB

    const int tid = threadIdx.x;
    // staging: 4 loads for A + 4 for B per K-tile; load l covers idx=tid+l*512
    const __bf16* ap[4]; const __bf16* bp[4];
    int dstoff[4];
#pragma unroll
    for (int l = 0; l < 4; l++) {
        int idx = tid + l * 512;
        int row = idx >> 3, ck = idx & 7;      // 256 rows x 8 chunks(16B)
        int cks = (ck ^ (row & 7)) * 8;        // swizzled source chunk (elems)
        int cl = min(mt * 256 + row, ne - 1);
        ap[l] = xb + (size_t)tlist[base + cl] * HH + cks;
        bp[l] = w + (size_t)(nt * 256 + row) * HH + cks;
        dstoff[l] = idx * 8;                   // linear LDS dest (elems)
    }

#define STAGE(bufi, kof) do {                                          \
    _Pragma("unroll")                                                  \
    for (int l = 0; l < 4; l++)                                        \
        load16_lds(ap[l] + (kof), &sm[bufi][0][dstoff[l]]);            \
    _Pragma("unroll")                                                  \
    for (int l = 0; l < 4; l++)                                        \
        load16_lds(bp[l] + (kof), &sm[bufi][1][dstoff[l]]);            \
} while (0)

    const int wid = tid >> 6, lane = tid & 63;
    const int wm = wid >> 2, wn = wid & 3;     // 2M x 4N waves
    const int l16 = lane & 15, quad = lane >> 4;
    const int rsw = l16 & 7;
    const int ckof0 = (quad ^ rsw) * 8;        // k-slice 0 chunk (elems)
    const int ckof1 = ((4 + quad) ^ rsw) * 8;  // k-slice 1 chunk
    const int arow = wm * 128 + l16;
    const int brow = wn * 64 + l16;

    f32x4v acc[8][4];
#pragma unroll
    for (int i = 0; i < 8; i++)
#pragma unroll
        for (int j = 0; j < 4; j++) acc[i][j] = (f32x4v)0.0f;

#define COMPUTE(bufi) do {                                                        \
    bf16x8 bfr[4][2];                                                             \
    _Pragma("unroll")                                                             \
    for (int j = 0; j < 4; j++) {                                                 \
        bfr[j][0] = *(const bf16x8*)&sm[bufi][1][(brow + j * 16) * 64 + ckof0];   \
        bfr[j][1] = *(const bf16x8*)&sm[bufi][1][(brow + j * 16) * 64 + ckof1];   \
    }                                                                             \
    _Pragma("unroll")                                                             \
    for (int h = 0; h < 2; h++) {                                                 \
        bf16x8 afr[4][2];                                                         \
        _Pragma("unroll")                                                         \
        for (int i2 = 0; i2 < 4; i2++) {                                          \
            int rr = (arow + (h * 4 + i2) * 16) * 64;                             \
            afr[i2][0] = *(const bf16x8*)&sm[bufi][0][rr + ckof0];                 \
            afr[i2][1] = *(const bf16x8*)&sm[bufi][0][rr + ckof1];                 \
        }                                                                         \
        __builtin_amdgcn_s_setprio(1);                                            \
        _Pragma("unroll")                                                         \
        for (int ks = 0; ks < 2; ks++)                                            \
            _Pragma("unroll")                                                     \
            for (int j = 0; j < 4; j++)                                           \
                _Pragma("unroll")                                                 \
                for (int i2 = 0; i2 < 4; i2++)                                    \
                    acc[h * 4 + i2][j] = __builtin_amdgcn_mfma_f32_16x16x32_bf16( \
                        afr[i2][ks], bfr[j][ks], acc[h * 4 + i2][j], 0, 0, 0);    \
        __builtin_amdgcn_s_setprio(0);                                            \
    }                                                                             \
} while (0)

    STAGE(0, 0);                               // prologue: tile 0 in flight
    for (int t = 0; t < 15; t++) {
        const int buf = t & 1;
        STAGE(buf ^ 1, (t + 1) * 64);          // tile t+1 -> other buffer
        VMCNT(8);                              // tile t landed; t+1 in flight
        __builtin_amdgcn_s_barrier();
        __builtin_amdgcn_sched_barrier(0);
        COMPUTE(buf);
        LGKM0;                                 // reads drained (rule #18)
        __builtin_amdgcn_sched_barrier(0);
        __builtin_amdgcn_s_barrier();
    }
    VMCNT(0);                                  // last tile (t=15, buf=1)
    __builtin_amdgcn_s_barrier();
    __builtin_amdgcn_sched_barrier(0);
    COMPUTE(1);

    // epilogue: j=2jj gate, j=2jj+1 up; real col = nt*128 + wn*32 + jj*16 + l16
#pragma unroll
    for (int i = 0; i < 8; i++) {
        const int mrow = mt * 256 + wm * 128 + i * 16 + quad * 4;
#pragma unroll
        for (int r = 0; r < 4; r++) {
            const int slot = mrow + r;
            if (slot < ne) {
                __bf16* hrow = hbuf + (size_t)(base + slot) * II + nt * 128 + wn * 32 + l16;
#pragma unroll
                for (int jj = 0; jj < 2; jj++) {
                    float g = acc[i][2 * jj][r], u = acc[i][2 * jj + 1][r];
                    float sgl = g / (1.0f + __expf(-g));
                    hrow[jj * 16] = (__bf16)(sgl * u);
                }
            }
        }
    }
#undef STAGE
#undef COMPUTE
}

// ---------------------------------------------------------------- down proj
// 128(M)x128(N), BK=32, wave tile 64x64, global_load_lds staging (verified).
__global__ __launch_bounds__(256, 3) void down_y(
        const __bf16* __restrict__ Wd, const __bf16* __restrict__ Wds,
        const __bf16* __restrict__ hbuf, float* __restrict__ ybuf,
        const int* __restrict__ nlist, const int* __restrict__ offs,
        const int* __restrict__ tlist, const float* __restrict__ wlist) {
    const int e = blockIdx.z;
    const int ne = nlist[e];
    const int bx = blockIdx.x;                 // [0,256): 8 nt x 32 mt
    const int nt = bx & 7;                     // XCD = nt
    const int mt = bx >> 3;
    if (mt * 128 >= ne) return;
    const int base = offs[e];
    const __bf16* wd = (e < EE) ? Wd + (size_t)e * HH * II : Wds;

    __shared__ __bf16 As[128 * 32];   // 8 KB
    __shared__ __bf16 Bs[128 * 32];   // 8 KB

    const int tid = threadIdx.x;
    const int r0 = tid >> 2;
    const int c  = tid & 3;
    const int cs = (c ^ ((r0 >> 1) & 3)) * 8;
    const int cl0 = min(mt * 128 + r0, ne - 1);
    const int cl1 = min(mt * 128 + r0 + 64, ne - 1);
    const __bf16* aptr0 = hbuf + (size_t)(base + cl0) * II + cs;
    const __bf16* aptr1 = hbuf + (size_t)(base + cl1) * II + cs;
    const __bf16* bptr0 = wd + (size_t)(nt * 128 + r0) * II + cs;
    const __bf16* bptr1 = wd + (size_t)(nt * 128 + r0 + 64) * II + cs;
    __bf16* ldsA0 = &As[tid * 8];
    __bf16* ldsA1 = &As[64 * 32 + tid * 8];
    __bf16* ldsB0 = &Bs[tid * 8];
    __bf16* ldsB1 = &Bs[64 * 32 + tid * 8];

    const int wid = tid >> 6, lane = tid & 63;
    const int wm = wid >> 1, wn = wid & 1;
    const int l16 = lane & 15, quad = lane >> 4;
    const int qsw = (quad ^ ((l16 >> 1) & 3)) * 8;

    f32x4v acc[4][4];
#pragma unroll
    for (int i = 0; i < 4; i++)
#pragma unroll
        for (int j = 0; j < 4; j++) acc[i][j] = (f32x4v)0.0f;

    for (int k0 = 0; k0 < II; k0 += 32) {
        __syncthreads();
        load16_lds(aptr0 + k0, ldsA0);
        load16_lds(aptr1 + k0, ldsA1);
        load16_lds(bptr0 + k0, ldsB0);
        load16_lds(bptr1 + k0, ldsB1);
        __syncthreads();
        bf16x8 a[4];
#pragma unroll
        for (int i = 0; i < 4; i++)
            a[i] = *(const bf16x8*)&As[(wm * 64 + i * 16 + l16) * 32 + qsw];
#pragma unroll
        for (int j = 0; j < 4; j++) {
            bf16x8 b = *(const bf16x8*)&Bs[(wn * 64 + j * 16 + l16) * 32 + qsw];
#pragma unroll
            for (int i = 0; i < 4; i++)
                acc[i][j] = __builtin_amdgcn_mfma_f32_16x16x32_bf16(a[i], b, acc[i][j], 0, 0, 0);
        }
    }
    // epilogue: ybuf[slot] = w_slot * acc (exactly one writer per cell)
#pragma unroll
    for (int i = 0; i < 4; i++) {
        const int mrow = mt * 128 + wm * 64 + i * 16 + quad * 4;
#pragma unroll
        for (int r = 0; r < 4; r++) {
            const int slot = mrow + r;
            if (slot < ne) {
                const int idx = base + slot;
                const float w = wlist[idx];
                float* orow = ybuf + (size_t)idx * HH + nt * 128 + wn * 64 + l16;
#pragma unroll
                for (int j = 0; j < 4; j++)
                    orow[j * 16] = w * acc[i][j][r];
            }
        }
    }
}

// ---------------------------------------------------------------- combine
// out[t] = ybuf[slot0(t)] + ybuf[slot1(t)] + ybuf[SHARED_BASE + t]
__global__ void combine_k(const float* __restrict__ ybuf, const int* __restrict__ inv,
                          float* __restrict__ out) {
    int idx = blockIdx.x * blockDim.x + threadIdx.x;   // NTOK*256 threads
    int t = idx >> 8, h4 = idx & 255;
    const f32x4v* y0 = (const f32x4v*)(ybuf + (size_t)inv[2 * t] * HH);
    const f32x4v* y1 = (const f32x4v*)(ybuf + (size_t)inv[2 * t + 1] * HH);
    const f32x4v* ys = (const f32x4v*)(ybuf + (size_t)(SHARED_BASE + t) * HH);
    f32x4v r = y0[h4] + y1[h4] + ys[h4];
    ((f32x4v*)(out + (size_t)t * HH))[h4] = r;
}

// ---------------------------------------------------------------- launch
extern "C" void kernel_launch(void* const* d_in, const int* in_sizes, int n_in,
                              void* d_out, int out_size, void* d_ws, size_t ws_size,
                              hipStream_t stream) {
    const float* x   = (const float*)d_in[0];
    const float* Wgs = (const float*)d_in[1];
    const float* Wus = (const float*)d_in[2];
    const float* Wds = (const float*)d_in[3];
    const float* Wg  = (const float*)d_in[4];
    const float* Wu  = (const float*)d_in[5];
    const float* Wd  = (const float*)d_in[6];
    const float* Wr  = (const float*)d_in[7];
    float* out = (float*)d_out;                        // [NTOK][HH]
    float* logits = out + (size_t)NTOK * HH;           // [NTOK][EE]

    // workspace layout (~216 MB):
    //   hbuf | xb | wgu (2*WEB) | wdb (WEB) | wgus (2*WSB) | wdsb (WSB) | meta
    // ybuf (50.3 MB fp32) ALIASES wgu (80.7 MB): wgu dead after gugemm;
    // down_y runs strictly after it on the stream.
    const size_t HB  = (size_t)NSLOT * II * 2;         // hbuf bf16
    const size_t XB  = (size_t)NTOK * HH * 2;          // xb bf16
    const size_t WEB = (size_t)EE * II * HH * 2;       // one routed weight set, bf16
    const size_t WSB = (size_t)II * HH * 2;            // one shared weight set, bf16

    char* ws = (char*)d_ws;
    __bf16* hbuf = (__bf16*)ws;
    __bf16* xb   = (__bf16*)(ws + HB);
    __bf16* wgu  = (__bf16*)(ws + HB + XB);
    float*  ybuf = (float*)wgu;                        // alias (see above)
    __bf16* wdb  = (__bf16*)(ws + HB + XB + 2 * WEB);
    __bf16* wgus = (__bf16*)(ws + HB + XB + 3 * WEB);
    __bf16* wdsb = (__bf16*)(ws + HB + XB + 3 * WEB + 2 * WSB);
    char* meta   = ws + HB + XB + 3 * WEB + 3 * WSB;
    int* counts = (int*)meta;            // 8
    int* cursor = counts + 8;            // 8
    int* nlist  = cursor + 8;            // 8
    int* offs   = nlist + 8;             // 8
    int* sel    = offs + 8;              // 2*NTOK
    int* tlist  = sel + 2 * NTOK;        // NSLOT
    float* wtop = (float*)(tlist + NSLOT);   // 2*NTOK
    float* wlist = wtop + 2 * NTOK;          // NSLOT
    int* inv    = (int*)(wlist + NSLOT);     // 2*NTOK

    hipMemsetAsync(counts, 0, 8 * sizeof(int), stream);

    prep_k<<<dim3(1024, 8), 256, 0, stream>>>(x, Wr, Wg, Wu, Wgs, Wus, Wd, Wds,
                                              xb, wgu, wgus, wdb, wdsb,
                                              logits, counts, sel, wtop, tlist, wlist);
    finalize_k<<<1, 64, 0, stream>>>(counts, cursor, nlist, offs);
    scatter_k<<<NTOK / 256, 256, 0, stream>>>(sel, wtop, cursor, tlist, wlist, inv);
    gugemm<<<dim3(352, 1, EE + 1), 512, 0, stream>>>(wgu, wgus, xb, hbuf,
                                                     nlist, offs, tlist);
    down_y<<<dim3(256, 1, EE + 1), 256, 0, stream>>>(wdb, wdsb, hbuf, ybuf,
                                                     nlist, offs, tlist, wlist);
    combine_k<<<NTOK, 256, 0, stream>>>(ybuf, inv, out);
}